// Round 4
// baseline (120.170 us; speedup 1.0000x reference)
//
#include <hip/hip_runtime.h>

// Periodic radius graph: out[i][j][k] = |(frac[j]-frac[i]+off[k]) @ cell|
// masked to (d2 > 1e-12 && d < 5.0), else 0. N=1024, 27 images.
// 113.2 MB fp32 output -> write floor ~18 us at 6.4 TB/s.
//
// R4 changes vs R3 (both bit-exact vs numpy: same mul/add ops, same order,
// no fma contraction -- verified by absmax 0.0 in R1-R3):
//  1. Shared-subexpression factoring across the 27 images:
//     fx in {dfx-1, dfx, dfx+1} -> 27 products p[axis][s][e] and 27 partial
//     sums (px+py) computed ONCE per pair; per-element work drops ~27->~12 ops.
//  2. Grid-stride G=4 tiles per block (1024 blocks = 4/CU, all resident):
//     gen g+1 compute overlaps gen g store writeback -> no compute/store convoy.

#define NATOMS 1024
#define NIMG 27
#define PAIRS_PER_BLOCK 256
#define FLOATS_PER_BLOCK (PAIRS_PER_BLOCK * NIMG)   // 6912 floats = 27648 B LDS
#define VEC4_PER_BLOCK (FLOATS_PER_BLOCK / 4)       // 1728
#define GENS 4

__global__ __launch_bounds__(256) void PeriodicRadiusGraph_kernel(
    const float* __restrict__ frac,   // [1024, 3]
    const float* __restrict__ cell,   // [3, 3]
    float* __restrict__ out)          // [1024, 1024, 27] flat
{
    __shared__ float tile[FLOATS_PER_BLOCK];

    const unsigned t = threadIdx.x;

    // cell rows (wave-uniform -> scalar loads), c[d][e]
    float c[3][3];
#pragma unroll
    for (int d = 0; d < 3; ++d)
#pragma unroll
        for (int e = 0; e < 3; ++e) c[d][e] = cell[3 * d + e];

    for (int g = 0; g < GENS; ++g) {
        const unsigned T = blockIdx.x * GENS + (unsigned)g;  // tile 0..4095
        const unsigned q = T * PAIRS_PER_BLOCK + t;          // pair i*1024+j
        const unsigned j = q & (NATOMS - 1u);
        const unsigned i = q >> 10;

        const float fix = frac[3u * i + 0u], fiy = frac[3u * i + 1u], fiz = frac[3u * i + 2u];
        const float fjx = frac[3u * j + 0u], fjy = frac[3u * j + 1u], fjz = frac[3u * j + 2u];

        const float df[3] = { fjx - fix, fjy - fiy, fjz - fiz };

        // fv[axis][s] = df + offset, offset = s-1 in {-1,0,+1}; the +0.0f is
        // the same source expression the bit-exact R1-R3 kernels used.
        float fv[3][3];
#pragma unroll
        for (int a = 0; a < 3; ++a) {
            fv[a][0] = df[a] + (-1.0f);
            fv[a][1] = df[a] + 0.0f;
            fv[a][2] = df[a] + 1.0f;
        }

        // products p[axis][s][e] = fv[axis][s] * c[axis][e]  (27 muls)
        float p[3][3][3];
#pragma unroll
        for (int a = 0; a < 3; ++a)
#pragma unroll
            for (int s = 0; s < 3; ++s)
#pragma unroll
                for (int e = 0; e < 3; ++e) p[a][s][e] = fv[a][s] * c[a][e];

        // partial sums sxy[sx][sy][e] = p[0][sx][e] + p[1][sy][e]  (27 adds)
        float sxy[3][3][3];
#pragma unroll
        for (int sx = 0; sx < 3; ++sx)
#pragma unroll
            for (int sy = 0; sy < 3; ++sy)
#pragma unroll
                for (int e = 0; e < 3; ++e) sxy[sx][sy][e] = p[0][sx][e] + p[1][sy][e];

        float* row = &tile[t * NIMG];
#pragma unroll
        for (int k = 0; k < NIMG; ++k) {
            const int sx = k / 9, sy = (k / 3) % 3, sz = k % 3;  // compile-time
            // vec_e = (fx*c0e + fy*c1e) + fz*c2e — same left-assoc order as ref
            const float vx = sxy[sx][sy][0] + p[2][sz][0];
            const float vy = sxy[sx][sy][1] + p[2][sz][1];
            const float vz = sxy[sx][sy][2] + p[2][sz][2];
            const float d2 = vx * vx + vy * vy + vz * vz;
            const float d  = __builtin_amdgcn_sqrtf(d2);  // mask from d2: exact
            row[k] = (d2 > 1e-12f && d2 < 25.0f) ? d : 0.0f;
        }

        __syncthreads();

        // Coalesced float4 write-out of this tile's flat 6912-float region.
        float4* out4 = (float4*)(out + (size_t)T * FLOATS_PER_BLOCK);
        const float4* tile4 = (const float4*)tile;
#pragma unroll
        for (int cc = 0; cc < 7; ++cc) {
            const int l = cc * 256 + (int)t;
            if (l < VEC4_PER_BLOCK) out4[l] = tile4[l];
        }

        __syncthreads();  // tile reusable for next generation
    }
}

extern "C" void kernel_launch(void* const* d_in, const int* in_sizes, int n_in,
                              void* d_out, int out_size, void* d_ws, size_t ws_size,
                              hipStream_t stream) {
    const float* frac = (const float*)d_in[0];
    const float* cell = (const float*)d_in[1];
    float* out = (float*)d_out;

    const int grid = (NATOMS * NATOMS) / (PAIRS_PER_BLOCK * GENS);  // 1024
    PeriodicRadiusGraph_kernel<<<grid, PAIRS_PER_BLOCK, 0, stream>>>(frac, cell, out);
}

// Round 5
// 119.170 us; speedup vs baseline: 1.0084x; 1.0084x over previous
//
#include <hip/hip_runtime.h>

// Periodic radius graph: out[i][j][k] = |(frac[j]-frac[i]+off[k]) @ cell|
// masked to (d2 > 1e-12 && d < 5.0), else 0. N=1024, 27 images.
// 113.2 MB fp32 output -> write floor ~18 us at 6.4 TB/s.
//
// R5: ZERO barriers. Each wave uses a PRIVATE 6912-B LDS chunk to transpose
// its 64 pairs x 27 floats into contiguous float4s, then streams them out.
// Wave-private RAW through LDS needs only lgkmcnt (compiler-inserted), no
// __syncthreads -> no block-wide phase convoy (the R2-R4 stall suspect:
// VALU cuts in R3/R4 moved nothing, so the ~48us kernel is stall-bound).
// Math identical to R4 (bit-exact vs numpy, absmax 0.0 in R1-R4).

#define NATOMS 1024
#define NIMG 27
#define THREADS 256
#define FLOATS_PER_WAVE (64 * NIMG)          // 1728 floats = 6912 B
#define VEC4_PER_WAVE (FLOATS_PER_WAVE / 4)  // 432
#define FLOATS_PER_BLOCK (THREADS * NIMG)    // 6912 floats = 27648 B LDS

__global__ __launch_bounds__(256) void PeriodicRadiusGraph_kernel(
    const float* __restrict__ frac,   // [1024, 3]
    const float* __restrict__ cell,   // [3, 3]
    float* __restrict__ out)          // [1024, 1024, 27] flat
{
    __shared__ float tile[FLOATS_PER_BLOCK];

    const unsigned t = threadIdx.x;
    const unsigned w = t >> 6;        // wave 0..3
    const unsigned l = t & 63u;       // lane

    const unsigned q = blockIdx.x * THREADS + t;  // pair i*1024 + j
    const unsigned j = q & (NATOMS - 1u);
    const unsigned i = q >> 10;                   // uniform per block

    // cell rows (wave-uniform -> scalar loads), c[d][e]
    float c[3][3];
#pragma unroll
    for (int d = 0; d < 3; ++d)
#pragma unroll
        for (int e = 0; e < 3; ++e) c[d][e] = cell[3 * d + e];

    const float fix = frac[3u * i + 0u], fiy = frac[3u * i + 1u], fiz = frac[3u * i + 2u];
    const float fjx = frac[3u * j + 0u], fjy = frac[3u * j + 1u], fjz = frac[3u * j + 2u];

    const float df[3] = { fjx - fix, fjy - fiy, fjz - fiz };

    // fv[axis][s] = df + (s-1); same source exprs as the bit-exact R1-R4.
    float fv[3][3];
#pragma unroll
    for (int a = 0; a < 3; ++a) {
        fv[a][0] = df[a] + (-1.0f);
        fv[a][1] = df[a] + 0.0f;
        fv[a][2] = df[a] + 1.0f;
    }

    // products p[axis][s][e] = fv[axis][s] * c[axis][e]  (27 muls)
    float p[3][3][3];
#pragma unroll
    for (int a = 0; a < 3; ++a)
#pragma unroll
        for (int s = 0; s < 3; ++s)
#pragma unroll
            for (int e = 0; e < 3; ++e) p[a][s][e] = fv[a][s] * c[a][e];

    // partial sums sxy[sx][sy][e] = p[0][sx][e] + p[1][sy][e]  (27 adds)
    float sxy[3][3][3];
#pragma unroll
    for (int sx = 0; sx < 3; ++sx)
#pragma unroll
        for (int sy = 0; sy < 3; ++sy)
#pragma unroll
            for (int e = 0; e < 3; ++e) sxy[sx][sy][e] = p[0][sx][e] + p[1][sy][e];

    // Row write: stride 27 dwords; gcd(27,32)=1 -> 2 lanes/bank = free.
    float* row = &tile[t * NIMG];
#pragma unroll
    for (int k = 0; k < NIMG; ++k) {
        const int sx = k / 9, sy = (k / 3) % 3, sz = k % 3;  // compile-time
        const float vx = sxy[sx][sy][0] + p[2][sz][0];
        const float vy = sxy[sx][sy][1] + p[2][sz][1];
        const float vz = sxy[sx][sy][2] + p[2][sz][2];
        const float d2 = vx * vx + vy * vy + vz * vz;
        const float d  = __builtin_amdgcn_sqrtf(d2);  // mask from d2: exact
        row[k] = (d2 > 1e-12f && d2 < 25.0f) ? d : 0.0f;
    }

    // NO __syncthreads: this wave reads back only its own chunk; the
    // compiler orders the RAW with lgkmcnt. Stores are fire-and-forget.
    const float4* tile4 = (const float4*)&tile[w * FLOATS_PER_WAVE];
    float4* out4 = (float4*)(out + (size_t)blockIdx.x * FLOATS_PER_BLOCK
                                 + (size_t)w * FLOATS_PER_WAVE);
#pragma unroll
    for (int r = 0; r < 7; ++r) {
        const unsigned v = r * 64u + l;          // 6 full rounds + 48-lane tail
        if (v < VEC4_PER_WAVE) out4[v] = tile4[v];
    }
}

extern "C" void kernel_launch(void* const* d_in, const int* in_sizes, int n_in,
                              void* d_out, int out_size, void* d_ws, size_t ws_size,
                              hipStream_t stream) {
    const float* frac = (const float*)d_in[0];
    const float* cell = (const float*)d_in[1];
    float* out = (float*)d_out;

    const int grid = (NATOMS * NATOMS) / THREADS;  // 4096 blocks, exact
    PeriodicRadiusGraph_kernel<<<grid, THREADS, 0, stream>>>(frac, cell, out);
}